// Round 22
// baseline (125.834 us; speedup 1.0000x reference)
//
#include <hip/hip_runtime.h>
#include <hip/hip_bf16.h>
#include <cstdint>

typedef unsigned short u16;
typedef __bf16 bf16x8 __attribute__((ext_vector_type(8)));
typedef float f32x4 __attribute__((ext_vector_type(4)));

#define S_LEN 2048
#define NH 16
#define DK 64
#define DM 1024

__device__ __forceinline__ u16 f2bf(float f) {
  union { float f; uint32_t u; } c; c.f = f;
  uint32_t u = c.u;
  u += 0x7fffu + ((u >> 16) & 1u);   // RNE
  return (u16)(u >> 16);
}

__device__ __forceinline__ void gl_lds16(const void* gsrc, void* ldst) {
  __builtin_amdgcn_global_load_lds(
      (const __attribute__((address_space(1))) unsigned int*)gsrc,
      (__attribute__((address_space(3))) unsigned int*)ldst,
      16, 0, 0);
}

#define MFMA16(a, b, c) __builtin_amdgcn_mfma_f32_16x16x32_bf16((a), (b), (c), 0, 0, 0)
#define VMW(N) asm volatile("s_waitcnt vmcnt(" #N ")" ::: "memory")
#define BARM() asm volatile("s_barrier" ::: "memory")

// ---------------- fused prep: fp32->bf16 convert + RoPE table + mask flags ----------------
__global__ __launch_bounds__(256) void prep_all(
    const float* x, const float* wq, const float* wk, const float* wv, const float* wo,
    const int* amask,
    u16* xb, u16* wqb, u16* wkb, u16* wvb, u16* wob, float2* tab, int* mflag)
{
  const int bid = blockIdx.x;
  if (bid < 2048) {
#pragma unroll
    for (int it = 0; it < 4; ++it) {
      size_t i = ((size_t)bid * 256 + threadIdx.x) * 4 + (size_t)it * 2097152u;
      const float* src; u16* dst; size_t off;
      if (i < 4194304u)      { src = x;  dst = xb;  off = i; }
      else if (i < 5242880u) { src = wq; dst = wqb; off = i - 4194304u; }
      else if (i < 6291456u) { src = wk; dst = wkb; off = i - 5242880u; }
      else if (i < 7340032u) { src = wv; dst = wvb; off = i - 6291456u; }
      else                   { src = wo; dst = wob; off = i - 7340032u; }
      float4 v = *(const float4*)(src + off);
      ushort4 o;
      o.x = f2bf(v.x); o.y = f2bf(v.y); o.z = f2bf(v.z); o.w = f2bf(v.w);
      *(ushort4*)(dst + off) = o;
    }
  } else if (bid < 2304) {
    int i = (bid - 2048) * 256 + threadIdx.x;
    int pos = i >> 5, f = i & 31;
    float inv = powf(10000.0f, -(float)f / 32.0f);
    float ang = (float)pos * inv;
    tab[i] = make_float2(cosf(ang), sinf(ang));
  } else {
    const int f = bid - 2304;           // 0..63: b = f>>5, tile = f&31
    if (threadIdx.x < 64) {
      const int b = f >> 5, t = f & 31;
      int v = amask[b * S_LEN + t * 64 + threadIdx.x];
      int all = (int)__all(v != 0);
      if (threadIdx.x == 0) mflag[f] = all;
    }
  }
}

// ================= QKV projection: 128x128 tile, BK=32, 3-buffer 2-deep prefetch =================
// Same 2-barrier step structure; stage(t+2) targets buf[(t+2)%3] = buf[(t-1)%3],
// safe because the end-barrier of step t-1 means all waves finished reading it.
// VMW(8) allows stages t+1,t+2 in flight, drains exactly stage(t). Tail: 8/4/0.
// LDS 48KB; grid 768 = 3 blocks/CU limits residency anyway -> zero occupancy cost.
__global__ __launch_bounds__(256, 3) void gemm_qkv32(
    const u16* xb, const u16* wqb, const u16* wkb, const u16* wvb,
    const float2* tab, u16* Qr, u16* Kr, u16* Vt)
{
  __shared__ __align__(16) u16 ldsA[3][128 * 32];
  __shared__ __align__(16) u16 ldsB[3][128 * 32];

  const int bid = blockIdx.x;
  const int xcd = bid & 7, v = bid >> 3;        // v 0..95
  const int m0 = (xcd * 4 + (v & 3)) * 128;     // 4 m-panels per XCD (32 total)
  const int nc = v >> 2;                        // 0..23
  const int z = nc >> 3;                        // 0=Q 1=K 2=V
  const int n0z = (nc & 7) * 128;
  const u16* Wz = (z == 0) ? wqb : ((z == 1) ? wkb : wvb);

  const int tid = threadIdx.x;
  const int w = tid >> 6, lane = tid & 63;
  const int l15 = lane & 15, g = lane >> 4;
  const int wm = (w >> 1) * 64, wn = (w & 1) * 64;
  const int lr4 = lane >> 2;
  const int scolb = ((lane & 3) * 16) ^ (((lane >> 3) & 3) << 4);

  f32x4 acc[4][4] = {};

  auto stage = [&](int buf, int kt) {
#pragma unroll
    for (int c = 0; c < 2; ++c) {
      const int rb = c * 64 + w * 16;
      const int row = rb + lr4;
      gl_lds16((const char*)(xb + (size_t)(m0 + row) * DM + kt) + scolb,
               (char*)&ldsA[buf][0] + rb * 64);
      gl_lds16((const char*)(Wz + (size_t)(n0z + row) * DM + kt) + scolb,
               (char*)&ldsB[buf][0] + rb * 64);
    }
  };

  stage(0, 0);
  stage(1, 32);
  int cur = 0;
  for (int kt = 0; kt < DM; kt += 32) {
    if (kt + 64 < DM) {
      const int nx2 = (cur + 2 >= 3) ? cur - 1 : cur + 2;
      stage(nx2, kt + 64);
      VMW(8);
    } else if (kt + 32 < DM) {
      VMW(4);
    } else {
      VMW(0);
    }
    BARM();
    bf16x8 af[4], bfr[4];
#pragma unroll
    for (int i = 0; i < 4; ++i) {
      const int ar = wm + i * 16 + l15;
      af[i] = *(const bf16x8*)((const char*)&ldsA[cur][0] + ar * 64 +
                               ((g * 16) ^ (((ar >> 1) & 3) << 4)));
      const int br = wn + i * 16 + l15;
      bfr[i] = *(const bf16x8*)((const char*)&ldsB[cur][0] + br * 64 +
                                ((g * 16) ^ (((br >> 1) & 3) << 4)));
    }
    __builtin_amdgcn_s_setprio(1);
#pragma unroll
    for (int i = 0; i < 4; ++i)
#pragma unroll
      for (int j = 0; j < 4; ++j)
        acc[i][j] = MFMA16(af[i], bfr[j], acc[i][j]);
    __builtin_amdgcn_s_setprio(0);
    BARM();
    cur = (cur + 1 >= 3) ? 0 : cur + 1;
  }

  u16* dst = (z == 0) ? Qr : Kr;
#pragma unroll
  for (int i = 0; i < 4; ++i) {
#pragma unroll
    for (int j = 0; j < 4; ++j) {
      const int n = n0z + wn + j * 16 + l15;
      const int h = n >> 6, d = n & 63;
#pragma unroll
      for (int r = 0; r < 4; ++r) {
        const int m = m0 + wm + i * 16 + g * 4 + r;
        const int b = m >> 11, s = m & 2047;
        float vv = acc[i][j][r];
        if (z < 2) {
          float p = __shfl_xor(vv, 1);
          float2 cs = tab[s * 32 + (d >> 1)];
          float o = vv * cs.x + ((d & 1) ? p : -p) * cs.y;
          if (z == 0) o *= 0.18033688011f;    // (1/sqrt(64)) * log2(e)
          dst[((size_t)(b * NH + h) * S_LEN + s) * DK + d] = f2bf(o);
        } else {
          Vt[((size_t)(b * NH + h) * DK + d) * S_LEN + s] = f2bf(vv);
        }
      }
    }
  }
}

// ================= output GEMM: 64x64 tile, BK=32, 3-buffer 2-deep prefetch =================
// Grid 1024 = 4 blocks/CU (24KB LDS). Stage = 2 loads -> VMW ladder 4/2/0.
__global__ __launch_bounds__(256, 4) void gemm_out44(const u16* ctx, const u16* wob, float* out) {
  __shared__ __align__(16) u16 ldsA[3][64 * 32];
  __shared__ __align__(16) u16 ldsB[3][64 * 32];

  const int bid = blockIdx.x;
  const int xcd = bid & 7, v = bid >> 3;        // v 0..127
  const int m0 = (xcd * 8 + (v & 7)) * 64;      // 64 m-panels
  const int n0 = (v >> 3) * 64;                 // 16 n-cols

  const int tid = threadIdx.x;
  const int w = tid >> 6, lane = tid & 63;
  const int l15 = lane & 15, g = lane >> 4;
  const int wm = (w >> 1) * 32, wn = (w & 1) * 32;
  const int lr4 = lane >> 2;
  const int scolb = ((lane & 3) * 16) ^ (((lane >> 3) & 3) << 4);

  f32x4 acc[2][2] = {};

  auto stage = [&](int buf, int kt) {
    const int rb = w * 16;
    const int row = rb + lr4;
    gl_lds16((const char*)(ctx + (size_t)(m0 + row) * DM + kt) + scolb,
             (char*)&ldsA[buf][0] + rb * 64);
    gl_lds16((const char*)(wob + (size_t)(n0 + row) * DM + kt) + scolb,
             (char*)&ldsB[buf][0] + rb * 64);
  };

  stage(0, 0);
  stage(1, 32);
  int cur = 0;
  for (int kt = 0; kt < DM; kt += 32) {
    if (kt + 64 < DM) {
      const int nx2 = (cur + 2 >= 3) ? cur - 1 : cur + 2;
      stage(nx2, kt + 64);
      VMW(4);
    } else if (kt + 32 < DM) {
      VMW(2);
    } else {
      VMW(0);
    }
    BARM();
    bf16x8 af[2], bfr[2];
#pragma unroll
    for (int i = 0; i < 2; ++i) {
      const int ar = wm + i * 16 + l15;
      af[i] = *(const bf16x8*)((const char*)&ldsA[cur][0] + ar * 64 +
                               ((g * 16) ^ (((ar >> 1) & 3) << 4)));
      const int br = wn + i * 16 + l15;
      bfr[i] = *(const bf16x8*)((const char*)&ldsB[cur][0] + br * 64 +
                                ((g * 16) ^ (((br >> 1) & 3) << 4)));
    }
    __builtin_amdgcn_s_setprio(1);
#pragma unroll
    for (int i = 0; i < 2; ++i)
#pragma unroll
      for (int j = 0; j < 2; ++j)
        acc[i][j] = MFMA16(af[i], bfr[j], acc[i][j]);
    __builtin_amdgcn_s_setprio(0);
    BARM();
    cur = (cur + 1 >= 3) ? 0 : cur + 1;
  }

#pragma unroll
  for (int i = 0; i < 2; ++i)
#pragma unroll
    for (int j = 0; j < 2; ++j)
#pragma unroll
      for (int r = 0; r < 4; ++r)
        out[(size_t)(m0 + wm + i * 16 + g * 4 + r) * DM + n0 + wn + j * 16 + l15] = acc[i][j][r];
}

// ---------------- causal flash attention (measured-best attn15, verbatim) ----------------
__global__ __launch_bounds__(256, 4) void attn15(
    const u16* Qr, const u16* Kr, const u16* Vt, const int* amask, const int* mflag,
    u16* ctx)
{
  __shared__ __align__(16) u16 ldsK[2][64 * 64];
  __shared__ __align__(16) u16 ldsV[2][64 * 64];
  __shared__ __align__(16) __bf16 plds[4][16 * 64];

  const int bh = blockIdx.x;
  const int band = 31 - blockIdx.y;     // 64-row band, longest first
  const int b = bh >> 4, h = bh & 15;
  const int tid = threadIdx.x, w = tid >> 6, lane = tid & 63;
  const int l15 = lane & 15, g = lane >> 4;
  const int r8 = lane >> 3;
  const int sw = ((lane & 7) * 16) ^ (r8 << 4);

  const int q0 = band * 64 + w * 16;
  const int dTile = band;               // tile containing the causal diagonal
  const int ntB = band + 1;

  const u16* Kb0 = Kr + (size_t)bh * S_LEN * DK;
  const u16* Vb0 = Vt + (size_t)bh * DK * S_LEN;
  const u16* Qb  = Qr + (size_t)bh * S_LEN * DK;

  bf16x8 qa0 = *(const bf16x8*)(Qb + (size_t)(q0 + l15) * DK + g * 8);
  bf16x8 qa1 = *(const bf16x8*)(Qb + (size_t)(q0 + l15) * DK + 32 + g * 8);

  union { u16 u[8]; bf16x8 v; } one_u;
#pragma unroll
  for (int i = 0; i < 8; ++i) one_u.u[i] = 0x3F80;
  const bf16x8 ones = one_u.v;

  float m[4];
  f32x4 lacc = {0.f, 0.f, 0.f, 0.f};
  f32x4 o[4];
#pragma unroll
  for (int r = 0; r < 4; ++r) m[r] = -3e38f;
#pragma unroll
  for (int dt = 0; dt < 4; ++dt) o[dt] = (f32x4){0.f, 0.f, 0.f, 0.f};

  auto stage = [&](int buf, int t) {
    const size_t kv0 = (size_t)t * 64;
#pragma unroll
    for (int c = 0; c < 2; ++c) {
      const int rb = w * 16 + c * 8;        // wave-uniform 8-row chunk base
      const int row = rb + r8;
      gl_lds16((const char*)(Kb0 + (kv0 + row) * DK) + sw,
               (char*)&ldsK[buf][0] + rb * 128);
      gl_lds16((const char*)(Vb0 + (size_t)row * S_LEN + kv0) + sw,
               (char*)&ldsV[buf][0] + rb * 128);
    }
  };

  stage(0, 0);
  int cur = 0;

  for (int t = 0; t < ntB; ++t) {
    if (t + 1 < ntB) { stage(cur ^ 1, t + 1); VMW(4); } else { VMW(0); }
    BARM();
    {
      const int kv0 = t * 64;
      const bool allok = mflag[(b << 5) + t] != 0;

      bf16x8 kb[4][2];
#pragma unroll
      for (int nt = 0; nt < 4; ++nt) {
        const int row = nt * 16 + l15;
#pragma unroll
        for (int ks = 0; ks < 2; ++ks)
          kb[nt][ks] = *(const bf16x8*)((const char*)&ldsK[cur][0] + row * 128 +
                                        ((ks * 64 + g * 16) ^ ((row & 7) << 4)));
      }
      f32x4 s[4];
#pragma unroll
      for (int nt = 0; nt < 4; ++nt) s[nt] = (f32x4){0.f, 0.f, 0.f, 0.f};
      __builtin_amdgcn_s_setprio(1);
#pragma unroll
      for (int nt = 0; nt < 4; ++nt) {
        s[nt] = MFMA16(qa0, kb[nt][0], s[nt]);
        s[nt] = MFMA16(qa1, kb[nt][1], s[nt]);
      }
      __builtin_amdgcn_s_setprio(0);

      if (!allok) {
#pragma unroll
        for (int nt = 0; nt < 4; ++nt) {
          const int pmv = amask[b * S_LEN + kv0 + nt * 16 + l15];
#pragma unroll
          for (int r = 0; r < 4; ++r)
            if (!pmv) s[nt][r] = -1e9f;
        }
      }
      if (t == dTile) {
#pragma unroll
        for (int nt = 0; nt < 4; ++nt) {
          const int kvc = kv0 + nt * 16 + l15;
#pragma unroll
          for (int r = 0; r < 4; ++r)
            s[nt][r] = (kvc <= q0 + g * 4 + r) ? s[nt][r] : -1e9f;
        }
      }

      // fast growth check: per-lane partial max only (no cross-lane reduce)
      float t4[4];
      bool grow = false;
#pragma unroll
      for (int r = 0; r < 4; ++r) {
        t4[r] = fmaxf(fmaxf(s[0][r], s[1][r]), fmaxf(s[2][r], s[3][r]));
        grow = grow || (t4[r] > m[r] + 11.5415603f);   // 8 * log2(e)
      }
      if (__any((int)grow)) {                // rare: exact reduce + rescale
#pragma unroll
        for (int r = 0; r < 4; ++r) {
          float t0 = t4[r];
          t0 = fmaxf(t0, __shfl_xor(t0, 1));
          t0 = fmaxf(t0, __shfl_xor(t0, 2));
          t0 = fmaxf(t0, __shfl_xor(t0, 4));
          t0 = fmaxf(t0, __shfl_xor(t0, 8));
          const float mnew = fmaxf(m[r], t0);
          const float alpha = exp2f(m[r] - mnew);
          m[r] = mnew;
          lacc[r] *= alpha;
#pragma unroll
          for (int dt = 0; dt < 4; ++dt) o[dt][r] *= alpha;
        }
      }
      __bf16* pw = &plds[w][0];
#pragma unroll
      for (int r = 0; r < 4; ++r) {
        const int row = g * 4 + r;
#pragma unroll
        for (int nt = 0; nt < 4; ++nt)
          pw[row * 64 + ((nt * 16 + l15) ^ ((row & 7) << 3))] =
              (__bf16)exp2f(s[nt][r] - m[r]);
      }
      bf16x8 pa0 = *(const bf16x8*)(pw + l15 * 64 + ((g * 8) ^ ((l15 & 7) << 3)));
      bf16x8 pa1 = *(const bf16x8*)(pw + l15 * 64 + ((32 + g * 8) ^ ((l15 & 7) << 3)));
      bf16x8 vb[4][2];
#pragma unroll
      for (int dt = 0; dt < 4; ++dt) {
        const int row = dt * 16 + l15;
#pragma unroll
        for (int ks = 0; ks < 2; ++ks)
          vb[dt][ks] = *(const bf16x8*)((const char*)&ldsV[cur][0] + row * 128 +
                                        ((ks * 64 + g * 16) ^ ((row & 7) << 4)));
      }
      __builtin_amdgcn_s_setprio(1);
      lacc = MFMA16(pa0, ones, lacc);
      lacc = MFMA16(pa1, ones, lacc);
#pragma unroll
      for (int dt = 0; dt < 4; ++dt) {
        o[dt] = MFMA16(pa0, vb[dt][0], o[dt]);
        o[dt] = MFMA16(pa1, vb[dt][1], o[dt]);
      }
      __builtin_amdgcn_s_setprio(0);
    }
    BARM();
    cur ^= 1;
  }

#pragma unroll
  for (int dt = 0; dt < 4; ++dt)
#pragma unroll
    for (int r = 0; r < 4; ++r) {
      const int q = q0 + g * 4 + r;
      ctx[((size_t)(b * S_LEN + q)) * DM + h * DK + dt * 16 + l15] =
          f2bf(o[dt][r] / lacc[r]);
    }
}

extern "C" void kernel_launch(void* const* d_in, const int* in_sizes, int n_in,
                              void* d_out, int out_size, void* d_ws, size_t ws_size,
                              hipStream_t stream) {
  const float* x   = (const float*)d_in[0];
  const int* amask = (const int*)d_in[1];
  const float* wq  = (const float*)d_in[2];
  const float* wk  = (const float*)d_in[3];
  const float* wv  = (const float*)d_in[4];
  const float* wo  = (const float*)d_in[5];
  float* out = (float*)d_out;

  char* ws = (char*)d_ws;
  u16* xb    = (u16*)(ws);                      // 8 MB
  u16* wqb   = (u16*)(ws + ( 8u << 20));        // 2 MB
  u16* wkb   = (u16*)(ws + (10u << 20));
  u16* wvb   = (u16*)(ws + (12u << 20));
  u16* wob   = (u16*)(ws + (14u << 20));
  float2* tab = (float2*)(ws + (16u << 20));    // 512 KB
  int* mflag = (int*)(ws + (16u << 20) + (768u << 10));   // 256 B
  u16* Qr    = (u16*)(ws + (17u << 20));        // 8 MB  [B,H,S,D]
  u16* Kr    = (u16*)(ws + (25u << 20));        // 8 MB  [B,H,S,D]
  u16* Vt    = (u16*)(ws + (33u << 20));        // 8 MB  [B,H,D,S]
  u16* ctx   = (u16*)(ws + (41u << 20));        // 8 MB  [B,S,H*D]

  hipLaunchKernelGGL(prep_all, dim3(2368), dim3(256), 0, stream,
                     x, wq, wk, wv, wo, amask, xb, wqb, wkb, wvb, wob, tab, mflag);
  hipLaunchKernelGGL(gemm_qkv32, dim3(768), dim3(256), 0, stream,
                     xb, wqb, wkb, wvb, tab, Qr, Kr, Vt);
  hipLaunchKernelGGL(attn15, dim3(32, 32), dim3(256), 0, stream,
                     Qr, Kr, Vt, amask, mflag, ctx);
  hipLaunchKernelGGL(gemm_out44, dim3(1024), dim3(256), 0, stream, ctx, wob, out);
}

// Round 23
// 124.670 us; speedup vs baseline: 1.0093x; 1.0093x over previous
//
#include <hip/hip_runtime.h>
#include <hip/hip_bf16.h>
#include <cstdint>

typedef unsigned short u16;
typedef __bf16 bf16x8 __attribute__((ext_vector_type(8)));
typedef float f32x4 __attribute__((ext_vector_type(4)));

#define S_LEN 2048
#define NH 16
#define DK 64
#define DM 1024

__device__ __forceinline__ u16 f2bf(float f) {
  union { float f; uint32_t u; } c; c.f = f;
  uint32_t u = c.u;
  u += 0x7fffu + ((u >> 16) & 1u);   // RNE
  return (u16)(u >> 16);
}

__device__ __forceinline__ void gl_lds16(const void* gsrc, void* ldst) {
  __builtin_amdgcn_global_load_lds(
      (const __attribute__((address_space(1))) unsigned int*)gsrc,
      (__attribute__((address_space(3))) unsigned int*)ldst,
      16, 0, 0);
}

#define MFMA16(a, b, c) __builtin_amdgcn_mfma_f32_16x16x32_bf16((a), (b), (c), 0, 0, 0)
#define VMW(N) asm volatile("s_waitcnt vmcnt(" #N ")" ::: "memory")
#define BARM() asm volatile("s_barrier" ::: "memory")

// ---------------- fused prep: fp32->bf16 convert + RoPE table + mask flags ----------------
__global__ __launch_bounds__(256) void prep_all(
    const float* x, const float* wq, const float* wk, const float* wv, const float* wo,
    const int* amask,
    u16* xb, u16* wqb, u16* wkb, u16* wvb, u16* wob, float2* tab, int* mflag)
{
  const int bid = blockIdx.x;
  if (bid < 2048) {
#pragma unroll
    for (int it = 0; it < 4; ++it) {
      size_t i = ((size_t)bid * 256 + threadIdx.x) * 4 + (size_t)it * 2097152u;
      const float* src; u16* dst; size_t off;
      if (i < 4194304u)      { src = x;  dst = xb;  off = i; }
      else if (i < 5242880u) { src = wq; dst = wqb; off = i - 4194304u; }
      else if (i < 6291456u) { src = wk; dst = wkb; off = i - 5242880u; }
      else if (i < 7340032u) { src = wv; dst = wvb; off = i - 6291456u; }
      else                   { src = wo; dst = wob; off = i - 7340032u; }
      float4 v = *(const float4*)(src + off);
      ushort4 o;
      o.x = f2bf(v.x); o.y = f2bf(v.y); o.z = f2bf(v.z); o.w = f2bf(v.w);
      *(ushort4*)(dst + off) = o;
    }
  } else if (bid < 2304) {
    int i = (bid - 2048) * 256 + threadIdx.x;
    int pos = i >> 5, f = i & 31;
    float inv = powf(10000.0f, -(float)f / 32.0f);
    float ang = (float)pos * inv;
    tab[i] = make_float2(cosf(ang), sinf(ang));
  } else {
    const int f = bid - 2304;           // 0..63: b = f>>5, tile = f&31
    if (threadIdx.x < 64) {
      const int b = f >> 5, t = f & 31;
      int v = amask[b * S_LEN + t * 64 + threadIdx.x];
      int all = (int)__all(v != 0);
      if (threadIdx.x == 0) mflag[f] = all;
    }
  }
}

// ================= QKV projection: 128x128 tile, BK=32, 4 blocks/CU =================
__global__ __launch_bounds__(256, 4) void gemm_qkv32(
    const u16* xb, const u16* wqb, const u16* wkb, const u16* wvb,
    const float2* tab, u16* Qr, u16* Kr, u16* Vt)
{
  __shared__ __align__(16) u16 ldsA[2][128 * 32];
  __shared__ __align__(16) u16 ldsB[2][128 * 32];

  const int bid = blockIdx.x;
  const int xcd = bid & 7, v = bid >> 3;        // v 0..95
  const int m0 = (xcd * 4 + (v & 3)) * 128;     // 4 m-panels per XCD (32 total)
  const int nc = v >> 2;                        // 0..23
  const int z = nc >> 3;                        // 0=Q 1=K 2=V
  const int n0z = (nc & 7) * 128;
  const u16* Wz = (z == 0) ? wqb : ((z == 1) ? wkb : wvb);

  const int tid = threadIdx.x;
  const int w = tid >> 6, lane = tid & 63;
  const int l15 = lane & 15, g = lane >> 4;
  const int wm = (w >> 1) * 64, wn = (w & 1) * 64;
  const int lr4 = lane >> 2;
  const int scolb = ((lane & 3) * 16) ^ (((lane >> 3) & 3) << 4);

  f32x4 acc[4][4] = {};

  auto stage = [&](int buf, int kt) {
#pragma unroll
    for (int c = 0; c < 2; ++c) {
      const int rb = c * 64 + w * 16;
      const int row = rb + lr4;
      gl_lds16((const char*)(xb + (size_t)(m0 + row) * DM + kt) + scolb,
               (char*)&ldsA[buf][0] + rb * 64);
      gl_lds16((const char*)(Wz + (size_t)(n0z + row) * DM + kt) + scolb,
               (char*)&ldsB[buf][0] + rb * 64);
    }
  };

  stage(0, 0);
  int cur = 0;
  for (int kt = 0; kt < DM; kt += 32) {
    if (kt + 32 < DM) { stage(cur ^ 1, kt + 32); VMW(4); } else { VMW(0); }
    BARM();
    bf16x8 af[4], bfr[4];
#pragma unroll
    for (int i = 0; i < 4; ++i) {
      const int ar = wm + i * 16 + l15;
      af[i] = *(const bf16x8*)((const char*)&ldsA[cur][0] + ar * 64 +
                               ((g * 16) ^ (((ar >> 1) & 3) << 4)));
      const int br = wn + i * 16 + l15;
      bfr[i] = *(const bf16x8*)((const char*)&ldsB[cur][0] + br * 64 +
                                ((g * 16) ^ (((br >> 1) & 3) << 4)));
    }
    __builtin_amdgcn_s_setprio(1);
#pragma unroll
    for (int i = 0; i < 4; ++i)
#pragma unroll
      for (int j = 0; j < 4; ++j)
        acc[i][j] = MFMA16(af[i], bfr[j], acc[i][j]);
    __builtin_amdgcn_s_setprio(0);
    BARM();
    cur ^= 1;
  }

  u16* dst = (z == 0) ? Qr : Kr;
#pragma unroll
  for (int i = 0; i < 4; ++i) {
#pragma unroll
    for (int j = 0; j < 4; ++j) {
      const int n = n0z + wn + j * 16 + l15;
      const int h = n >> 6, d = n & 63;
#pragma unroll
      for (int r = 0; r < 4; ++r) {
        const int m = m0 + wm + i * 16 + g * 4 + r;
        const int b = m >> 11, s = m & 2047;
        float vv = acc[i][j][r];
        if (z < 2) {
          float p = __shfl_xor(vv, 1);
          float2 cs = tab[s * 32 + (d >> 1)];
          float o = vv * cs.x + ((d & 1) ? p : -p) * cs.y;
          if (z == 0) o *= 0.18033688011f;    // (1/sqrt(64)) * log2(e)
          dst[((size_t)(b * NH + h) * S_LEN + s) * DK + d] = f2bf(o);
        } else {
          Vt[((size_t)(b * NH + h) * DK + d) * S_LEN + s] = f2bf(vv);
        }
      }
    }
  }
}

// ================= output GEMM: 64x64 tile, BK=32, grid 1024 = 4 blocks/CU =================
__global__ __launch_bounds__(256, 6) void gemm_out44(const u16* ctx, const u16* wob, float* out) {
  __shared__ __align__(16) u16 ldsA[2][64 * 32];
  __shared__ __align__(16) u16 ldsB[2][64 * 32];

  const int bid = blockIdx.x;
  const int xcd = bid & 7, v = bid >> 3;        // v 0..127
  const int m0 = (xcd * 8 + (v & 7)) * 64;      // 64 m-panels
  const int n0 = (v >> 3) * 64;                 // 16 n-cols

  const int tid = threadIdx.x;
  const int w = tid >> 6, lane = tid & 63;
  const int l15 = lane & 15, g = lane >> 4;
  const int wm = (w >> 1) * 32, wn = (w & 1) * 32;
  const int lr4 = lane >> 2;
  const int scolb = ((lane & 3) * 16) ^ (((lane >> 3) & 3) << 4);

  f32x4 acc[2][2] = {};

  auto stage = [&](int buf, int kt) {
    const int rb = w * 16;
    const int row = rb + lr4;
    gl_lds16((const char*)(ctx + (size_t)(m0 + row) * DM + kt) + scolb,
             (char*)&ldsA[buf][0] + rb * 64);
    gl_lds16((const char*)(wob + (size_t)(n0 + row) * DM + kt) + scolb,
             (char*)&ldsB[buf][0] + rb * 64);
  };

  stage(0, 0);
  int cur = 0;
  for (int kt = 0; kt < DM; kt += 32) {
    if (kt + 32 < DM) { stage(cur ^ 1, kt + 32); VMW(2); } else { VMW(0); }
    BARM();
    bf16x8 af[2], bfr[2];
#pragma unroll
    for (int i = 0; i < 2; ++i) {
      const int ar = wm + i * 16 + l15;
      af[i] = *(const bf16x8*)((const char*)&ldsA[cur][0] + ar * 64 +
                               ((g * 16) ^ (((ar >> 1) & 3) << 4)));
      const int br = wn + i * 16 + l15;
      bfr[i] = *(const bf16x8*)((const char*)&ldsB[cur][0] + br * 64 +
                                ((g * 16) ^ (((br >> 1) & 3) << 4)));
    }
    __builtin_amdgcn_s_setprio(1);
#pragma unroll
    for (int i = 0; i < 2; ++i)
#pragma unroll
      for (int j = 0; j < 2; ++j)
        acc[i][j] = MFMA16(af[i], bfr[j], acc[i][j]);
    __builtin_amdgcn_s_setprio(0);
    BARM();
    cur ^= 1;
  }

#pragma unroll
  for (int i = 0; i < 2; ++i)
#pragma unroll
    for (int j = 0; j < 2; ++j)
#pragma unroll
      for (int r = 0; r < 4; ++r)
        out[(size_t)(m0 + wm + i * 16 + g * 4 + r) * DM + n0 + wn + j * 16 + l15] = acc[i][j][r];
}

// ---------------- causal flash attention (measured-best attn15, verbatim) ----------------
__global__ __launch_bounds__(256, 4) void attn15(
    const u16* Qr, const u16* Kr, const u16* Vt, const int* amask, const int* mflag,
    u16* ctx)
{
  __shared__ __align__(16) u16 ldsK[2][64 * 64];
  __shared__ __align__(16) u16 ldsV[2][64 * 64];
  __shared__ __align__(16) __bf16 plds[4][16 * 64];

  const int bh = blockIdx.x;
  const int band = 31 - blockIdx.y;     // 64-row band, longest first
  const int b = bh >> 4, h = bh & 15;
  const int tid = threadIdx.x, w = tid >> 6, lane = tid & 63;
  const int l15 = lane & 15, g = lane >> 4;
  const int r8 = lane >> 3;
  const int sw = ((lane & 7) * 16) ^ (r8 << 4);

  const int q0 = band * 64 + w * 16;
  const int dTile = band;               // tile containing the causal diagonal
  const int ntB = band + 1;

  const u16* Kb0 = Kr + (size_t)bh * S_LEN * DK;
  const u16* Vb0 = Vt + (size_t)bh * DK * S_LEN;
  const u16* Qb  = Qr + (size_t)bh * S_LEN * DK;

  bf16x8 qa0 = *(const bf16x8*)(Qb + (size_t)(q0 + l15) * DK + g * 8);
  bf16x8 qa1 = *(const bf16x8*)(Qb + (size_t)(q0 + l15) * DK + 32 + g * 8);

  union { u16 u[8]; bf16x8 v; } one_u;
#pragma unroll
  for (int i = 0; i < 8; ++i) one_u.u[i] = 0x3F80;
  const bf16x8 ones = one_u.v;

  float m[4];
  f32x4 lacc = {0.f, 0.f, 0.f, 0.f};
  f32x4 o[4];
#pragma unroll
  for (int r = 0; r < 4; ++r) m[r] = -3e38f;
#pragma unroll
  for (int dt = 0; dt < 4; ++dt) o[dt] = (f32x4){0.f, 0.f, 0.f, 0.f};

  auto stage = [&](int buf, int t) {
    const size_t kv0 = (size_t)t * 64;
#pragma unroll
    for (int c = 0; c < 2; ++c) {
      const int rb = w * 16 + c * 8;        // wave-uniform 8-row chunk base
      const int row = rb + r8;
      gl_lds16((const char*)(Kb0 + (kv0 + row) * DK) + sw,
               (char*)&ldsK[buf][0] + rb * 128);
      gl_lds16((const char*)(Vb0 + (size_t)row * S_LEN + kv0) + sw,
               (char*)&ldsV[buf][0] + rb * 128);
    }
  };

  stage(0, 0);
  int cur = 0;

  for (int t = 0; t < ntB; ++t) {
    if (t + 1 < ntB) { stage(cur ^ 1, t + 1); VMW(4); } else { VMW(0); }
    BARM();
    {
      const int kv0 = t * 64;
      const bool allok = mflag[(b << 5) + t] != 0;

      bf16x8 kb[4][2];
#pragma unroll
      for (int nt = 0; nt < 4; ++nt) {
        const int row = nt * 16 + l15;
#pragma unroll
        for (int ks = 0; ks < 2; ++ks)
          kb[nt][ks] = *(const bf16x8*)((const char*)&ldsK[cur][0] + row * 128 +
                                        ((ks * 64 + g * 16) ^ ((row & 7) << 4)));
      }
      f32x4 s[4];
#pragma unroll
      for (int nt = 0; nt < 4; ++nt) s[nt] = (f32x4){0.f, 0.f, 0.f, 0.f};
      __builtin_amdgcn_s_setprio(1);
#pragma unroll
      for (int nt = 0; nt < 4; ++nt) {
        s[nt] = MFMA16(qa0, kb[nt][0], s[nt]);
        s[nt] = MFMA16(qa1, kb[nt][1], s[nt]);
      }
      __builtin_amdgcn_s_setprio(0);

      if (!allok) {
#pragma unroll
        for (int nt = 0; nt < 4; ++nt) {
          const int pmv = amask[b * S_LEN + kv0 + nt * 16 + l15];
#pragma unroll
          for (int r = 0; r < 4; ++r)
            if (!pmv) s[nt][r] = -1e9f;
        }
      }
      if (t == dTile) {
#pragma unroll
        for (int nt = 0; nt < 4; ++nt) {
          const int kvc = kv0 + nt * 16 + l15;
#pragma unroll
          for (int r = 0; r < 4; ++r)
            s[nt][r] = (kvc <= q0 + g * 4 + r) ? s[nt][r] : -1e9f;
        }
      }

      // fast growth check: per-lane partial max only (no cross-lane reduce)
      float t4[4];
      bool grow = false;
#pragma unroll
      for (int r = 0; r < 4; ++r) {
        t4[r] = fmaxf(fmaxf(s[0][r], s[1][r]), fmaxf(s[2][r], s[3][r]));
        grow = grow || (t4[r] > m[r] + 11.5415603f);   // 8 * log2(e)
      }
      if (__any((int)grow)) {                // rare: exact reduce + rescale
#pragma unroll
        for (int r = 0; r < 4; ++r) {
          float t0 = t4[r];
          t0 = fmaxf(t0, __shfl_xor(t0, 1));
          t0 = fmaxf(t0, __shfl_xor(t0, 2));
          t0 = fmaxf(t0, __shfl_xor(t0, 4));
          t0 = fmaxf(t0, __shfl_xor(t0, 8));
          const float mnew = fmaxf(m[r], t0);
          const float alpha = exp2f(m[r] - mnew);
          m[r] = mnew;
          lacc[r] *= alpha;
#pragma unroll
          for (int dt = 0; dt < 4; ++dt) o[dt][r] *= alpha;
        }
      }
      __bf16* pw = &plds[w][0];
#pragma unroll
      for (int r = 0; r < 4; ++r) {
        const int row = g * 4 + r;
#pragma unroll
        for (int nt = 0; nt < 4; ++nt)
          pw[row * 64 + ((nt * 16 + l15) ^ ((row & 7) << 3))] =
              (__bf16)exp2f(s[nt][r] - m[r]);
      }
      bf16x8 pa0 = *(const bf16x8*)(pw + l15 * 64 + ((g * 8) ^ ((l15 & 7) << 3)));
      bf16x8 pa1 = *(const bf16x8*)(pw + l15 * 64 + ((32 + g * 8) ^ ((l15 & 7) << 3)));
      bf16x8 vb[4][2];
#pragma unroll
      for (int dt = 0; dt < 4; ++dt) {
        const int row = dt * 16 + l15;
#pragma unroll
        for (int ks = 0; ks < 2; ++ks)
          vb[dt][ks] = *(const bf16x8*)((const char*)&ldsV[cur][0] + row * 128 +
                                        ((ks * 64 + g * 16) ^ ((row & 7) << 4)));
      }
      __builtin_amdgcn_s_setprio(1);
      lacc = MFMA16(pa0, ones, lacc);
      lacc = MFMA16(pa1, ones, lacc);
#pragma unroll
      for (int dt = 0; dt < 4; ++dt) {
        o[dt] = MFMA16(pa0, vb[dt][0], o[dt]);
        o[dt] = MFMA16(pa1, vb[dt][1], o[dt]);
      }
      __builtin_amdgcn_s_setprio(0);
    }
    BARM();
    cur ^= 1;
  }

#pragma unroll
  for (int dt = 0; dt < 4; ++dt)
#pragma unroll
    for (int r = 0; r < 4; ++r) {
      const int q = q0 + g * 4 + r;
      ctx[((size_t)(b * S_LEN + q)) * DM + h * DK + dt * 16 + l15] =
          f2bf(o[dt][r] / lacc[r]);
    }
}

extern "C" void kernel_launch(void* const* d_in, const int* in_sizes, int n_in,
                              void* d_out, int out_size, void* d_ws, size_t ws_size,
                              hipStream_t stream) {
  const float* x   = (const float*)d_in[0];
  const int* amask = (const int*)d_in[1];
  const float* wq  = (const float*)d_in[2];
  const float* wk  = (const float*)d_in[3];
  const float* wv  = (const float*)d_in[4];
  const float* wo  = (const float*)d_in[5];
  float* out = (float*)d_out;

  char* ws = (char*)d_ws;
  u16* xb    = (u16*)(ws);                      // 8 MB
  u16* wqb   = (u16*)(ws + ( 8u << 20));        // 2 MB
  u16* wkb   = (u16*)(ws + (10u << 20));
  u16* wvb   = (u16*)(ws + (12u << 20));
  u16* wob   = (u16*)(ws + (14u << 20));
  float2* tab = (float2*)(ws + (16u << 20));    // 512 KB
  int* mflag = (int*)(ws + (16u << 20) + (768u << 10));   // 256 B
  u16* Qr    = (u16*)(ws + (17u << 20));        // 8 MB  [B,H,S,D]
  u16* Kr    = (u16*)(ws + (25u << 20));        // 8 MB  [B,H,S,D]
  u16* Vt    = (u16*)(ws + (33u << 20));        // 8 MB  [B,H,D,S]
  u16* ctx   = (u16*)(ws + (41u << 20));        // 8 MB  [B,S,H*D]

  hipLaunchKernelGGL(prep_all, dim3(2368), dim3(256), 0, stream,
                     x, wq, wk, wv, wo, amask, xb, wqb, wkb, wvb, wob, tab, mflag);
  hipLaunchKernelGGL(gemm_qkv32, dim3(768), dim3(256), 0, stream,
                     xb, wqb, wkb, wvb, tab, Qr, Kr, Vt);
  hipLaunchKernelGGL(attn15, dim3(32, 32), dim3(256), 0, stream,
                     Qr, Kr, Vt, amask, mflag, ctx);
  hipLaunchKernelGGL(gemm_out44, dim3(1024), dim3(256), 0, stream, ctx, wob, out);
}

// Round 24
// 124.437 us; speedup vs baseline: 1.0112x; 1.0019x over previous
//
#include <hip/hip_runtime.h>
#include <hip/hip_bf16.h>
#include <cstdint>

typedef unsigned short u16;
typedef __bf16 bf16x8 __attribute__((ext_vector_type(8)));
typedef float f32x4 __attribute__((ext_vector_type(4)));

#define S_LEN 2048
#define NH 16
#define DK 64
#define DM 1024

__device__ __forceinline__ u16 f2bf(float f) {
  union { float f; uint32_t u; } c; c.f = f;
  uint32_t u = c.u;
  u += 0x7fffu + ((u >> 16) & 1u);   // RNE
  return (u16)(u >> 16);
}

__device__ __forceinline__ void gl_lds16(const void* gsrc, void* ldst) {
  __builtin_amdgcn_global_load_lds(
      (const __attribute__((address_space(1))) unsigned int*)gsrc,
      (__attribute__((address_space(3))) unsigned int*)ldst,
      16, 0, 0);
}

#define MFMA16(a, b, c) __builtin_amdgcn_mfma_f32_16x16x32_bf16((a), (b), (c), 0, 0, 0)
#define VMW(N) asm volatile("s_waitcnt vmcnt(" #N ")" ::: "memory")
#define BARM() asm volatile("s_barrier" ::: "memory")

// ---------------- fused prep: fp32->bf16 convert + RoPE table + mask flags ----------------
__global__ __launch_bounds__(256) void prep_all(
    const float* x, const float* wq, const float* wk, const float* wv, const float* wo,
    const int* amask,
    u16* xb, u16* wqb, u16* wkb, u16* wvb, u16* wob, float2* tab, int* mflag)
{
  const int bid = blockIdx.x;
  if (bid < 2048) {
#pragma unroll
    for (int it = 0; it < 4; ++it) {
      size_t i = ((size_t)bid * 256 + threadIdx.x) * 4 + (size_t)it * 2097152u;
      const float* src; u16* dst; size_t off;
      if (i < 4194304u)      { src = x;  dst = xb;  off = i; }
      else if (i < 5242880u) { src = wq; dst = wqb; off = i - 4194304u; }
      else if (i < 6291456u) { src = wk; dst = wkb; off = i - 5242880u; }
      else if (i < 7340032u) { src = wv; dst = wvb; off = i - 6291456u; }
      else                   { src = wo; dst = wob; off = i - 7340032u; }
      float4 v = *(const float4*)(src + off);
      ushort4 o;
      o.x = f2bf(v.x); o.y = f2bf(v.y); o.z = f2bf(v.z); o.w = f2bf(v.w);
      *(ushort4*)(dst + off) = o;
    }
  } else if (bid < 2304) {
    int i = (bid - 2048) * 256 + threadIdx.x;
    int pos = i >> 5, f = i & 31;
    float inv = powf(10000.0f, -(float)f / 32.0f);
    float ang = (float)pos * inv;
    tab[i] = make_float2(cosf(ang), sinf(ang));
  } else {
    const int f = bid - 2304;           // 0..63: b = f>>5, tile = f&31
    if (threadIdx.x < 64) {
      const int b = f >> 5, t = f & 31;
      int v = amask[b * S_LEN + t * 64 + threadIdx.x];
      int all = (int)__all(v != 0);
      if (threadIdx.x == 0) mflag[f] = all;
    }
  }
}

// ================= QKV projection: 128x128 tile, BK=32, 4 blocks/CU =================
__global__ __launch_bounds__(256, 4) void gemm_qkv32(
    const u16* xb, const u16* wqb, const u16* wkb, const u16* wvb,
    const float2* tab, u16* Qr, u16* Kr, u16* Vt)
{
  __shared__ __align__(16) u16 ldsA[2][128 * 32];
  __shared__ __align__(16) u16 ldsB[2][128 * 32];

  const int bid = blockIdx.x;
  const int xcd = bid & 7, v = bid >> 3;        // v 0..95
  const int m0 = (xcd * 4 + (v & 3)) * 128;     // 4 m-panels per XCD (32 total)
  const int nc = v >> 2;                        // 0..23
  const int z = nc >> 3;                        // 0=Q 1=K 2=V
  const int n0z = (nc & 7) * 128;
  const u16* Wz = (z == 0) ? wqb : ((z == 1) ? wkb : wvb);

  const int tid = threadIdx.x;
  const int w = tid >> 6, lane = tid & 63;
  const int l15 = lane & 15, g = lane >> 4;
  const int wm = (w >> 1) * 64, wn = (w & 1) * 64;
  const int lr4 = lane >> 2;
  const int scolb = ((lane & 3) * 16) ^ (((lane >> 3) & 3) << 4);

  f32x4 acc[4][4] = {};

  auto stage = [&](int buf, int kt) {
#pragma unroll
    for (int c = 0; c < 2; ++c) {
      const int rb = c * 64 + w * 16;
      const int row = rb + lr4;
      gl_lds16((const char*)(xb + (size_t)(m0 + row) * DM + kt) + scolb,
               (char*)&ldsA[buf][0] + rb * 64);
      gl_lds16((const char*)(Wz + (size_t)(n0z + row) * DM + kt) + scolb,
               (char*)&ldsB[buf][0] + rb * 64);
    }
  };

  stage(0, 0);
  int cur = 0;
  for (int kt = 0; kt < DM; kt += 32) {
    if (kt + 32 < DM) { stage(cur ^ 1, kt + 32); VMW(4); } else { VMW(0); }
    BARM();
    bf16x8 af[4], bfr[4];
#pragma unroll
    for (int i = 0; i < 4; ++i) {
      const int ar = wm + i * 16 + l15;
      af[i] = *(const bf16x8*)((const char*)&ldsA[cur][0] + ar * 64 +
                               ((g * 16) ^ (((ar >> 1) & 3) << 4)));
      const int br = wn + i * 16 + l15;
      bfr[i] = *(const bf16x8*)((const char*)&ldsB[cur][0] + br * 64 +
                                ((g * 16) ^ (((br >> 1) & 3) << 4)));
    }
    __builtin_amdgcn_s_setprio(1);
#pragma unroll
    for (int i = 0; i < 4; ++i)
#pragma unroll
      for (int j = 0; j < 4; ++j)
        acc[i][j] = MFMA16(af[i], bfr[j], acc[i][j]);
    __builtin_amdgcn_s_setprio(0);
    BARM();
    cur ^= 1;
  }

  u16* dst = (z == 0) ? Qr : Kr;
#pragma unroll
  for (int i = 0; i < 4; ++i) {
#pragma unroll
    for (int j = 0; j < 4; ++j) {
      const int n = n0z + wn + j * 16 + l15;
      const int h = n >> 6, d = n & 63;
#pragma unroll
      for (int r = 0; r < 4; ++r) {
        const int m = m0 + wm + i * 16 + g * 4 + r;
        const int b = m >> 11, s = m & 2047;
        float vv = acc[i][j][r];
        if (z < 2) {
          float p = __shfl_xor(vv, 1);
          float2 cs = tab[s * 32 + (d >> 1)];
          float o = vv * cs.x + ((d & 1) ? p : -p) * cs.y;
          if (z == 0) o *= 0.18033688011f;    // (1/sqrt(64)) * log2(e)
          dst[((size_t)(b * NH + h) * S_LEN + s) * DK + d] = f2bf(o);
        } else {
          Vt[((size_t)(b * NH + h) * DK + d) * S_LEN + s] = f2bf(vv);
        }
      }
    }
  }
}

// ================= output GEMM: 64x64 tile, BK=32, grid 1024 = 4 blocks/CU =================
__global__ __launch_bounds__(256, 6) void gemm_out44(const u16* ctx, const u16* wob, float* out) {
  __shared__ __align__(16) u16 ldsA[2][64 * 32];
  __shared__ __align__(16) u16 ldsB[2][64 * 32];

  const int bid = blockIdx.x;
  const int xcd = bid & 7, v = bid >> 3;        // v 0..127
  const int m0 = (xcd * 8 + (v & 7)) * 64;      // 64 m-panels
  const int n0 = (v >> 3) * 64;                 // 16 n-cols

  const int tid = threadIdx.x;
  const int w = tid >> 6, lane = tid & 63;
  const int l15 = lane & 15, g = lane >> 4;
  const int wm = (w >> 1) * 32, wn = (w & 1) * 32;
  const int lr4 = lane >> 2;
  const int scolb = ((lane & 3) * 16) ^ (((lane >> 3) & 3) << 4);

  f32x4 acc[2][2] = {};

  auto stage = [&](int buf, int kt) {
    const int rb = w * 16;
    const int row = rb + lr4;
    gl_lds16((const char*)(ctx + (size_t)(m0 + row) * DM + kt) + scolb,
             (char*)&ldsA[buf][0] + rb * 64);
    gl_lds16((const char*)(wob + (size_t)(n0 + row) * DM + kt) + scolb,
             (char*)&ldsB[buf][0] + rb * 64);
  };

  stage(0, 0);
  int cur = 0;
  for (int kt = 0; kt < DM; kt += 32) {
    if (kt + 32 < DM) { stage(cur ^ 1, kt + 32); VMW(2); } else { VMW(0); }
    BARM();
    bf16x8 af[2], bfr[2];
#pragma unroll
    for (int i = 0; i < 2; ++i) {
      const int ar = wm + i * 16 + l15;
      af[i] = *(const bf16x8*)((const char*)&ldsA[cur][0] + ar * 64 +
                               ((g * 16) ^ (((ar >> 1) & 3) << 4)));
      const int br = wn + i * 16 + l15;
      bfr[i] = *(const bf16x8*)((const char*)&ldsB[cur][0] + br * 64 +
                                ((g * 16) ^ (((br >> 1) & 3) << 4)));
    }
    __builtin_amdgcn_s_setprio(1);
#pragma unroll
    for (int i = 0; i < 2; ++i)
#pragma unroll
      for (int j = 0; j < 2; ++j)
        acc[i][j] = MFMA16(af[i], bfr[j], acc[i][j]);
    __builtin_amdgcn_s_setprio(0);
    BARM();
    cur ^= 1;
  }

#pragma unroll
  for (int i = 0; i < 2; ++i)
#pragma unroll
    for (int j = 0; j < 2; ++j)
#pragma unroll
      for (int r = 0; r < 4; ++r)
        out[(size_t)(m0 + wm + i * 16 + g * 4 + r) * DM + n0 + wn + j * 16 + l15] = acc[i][j][r];
}

// ---------------- causal flash attention (measured-best attn15, verbatim) ----------------
__global__ __launch_bounds__(256, 4) void attn15(
    const u16* Qr, const u16* Kr, const u16* Vt, const int* amask, const int* mflag,
    u16* ctx)
{
  __shared__ __align__(16) u16 ldsK[2][64 * 64];
  __shared__ __align__(16) u16 ldsV[2][64 * 64];
  __shared__ __align__(16) __bf16 plds[4][16 * 64];

  const int bh = blockIdx.x;
  const int band = 31 - blockIdx.y;     // 64-row band, longest first
  const int b = bh >> 4, h = bh & 15;
  const int tid = threadIdx.x, w = tid >> 6, lane = tid & 63;
  const int l15 = lane & 15, g = lane >> 4;
  const int r8 = lane >> 3;
  const int sw = ((lane & 7) * 16) ^ (r8 << 4);

  const int q0 = band * 64 + w * 16;
  const int dTile = band;               // tile containing the causal diagonal
  const int ntB = band + 1;

  const u16* Kb0 = Kr + (size_t)bh * S_LEN * DK;
  const u16* Vb0 = Vt + (size_t)bh * DK * S_LEN;
  const u16* Qb  = Qr + (size_t)bh * S_LEN * DK;

  bf16x8 qa0 = *(const bf16x8*)(Qb + (size_t)(q0 + l15) * DK + g * 8);
  bf16x8 qa1 = *(const bf16x8*)(Qb + (size_t)(q0 + l15) * DK + 32 + g * 8);

  union { u16 u[8]; bf16x8 v; } one_u;
#pragma unroll
  for (int i = 0; i < 8; ++i) one_u.u[i] = 0x3F80;
  const bf16x8 ones = one_u.v;

  float m[4];
  f32x4 lacc = {0.f, 0.f, 0.f, 0.f};
  f32x4 o[4];
#pragma unroll
  for (int r = 0; r < 4; ++r) m[r] = -3e38f;
#pragma unroll
  for (int dt = 0; dt < 4; ++dt) o[dt] = (f32x4){0.f, 0.f, 0.f, 0.f};

  auto stage = [&](int buf, int t) {
    const size_t kv0 = (size_t)t * 64;
#pragma unroll
    for (int c = 0; c < 2; ++c) {
      const int rb = w * 16 + c * 8;        // wave-uniform 8-row chunk base
      const int row = rb + r8;
      gl_lds16((const char*)(Kb0 + (kv0 + row) * DK) + sw,
               (char*)&ldsK[buf][0] + rb * 128);
      gl_lds16((const char*)(Vb0 + (size_t)row * S_LEN + kv0) + sw,
               (char*)&ldsV[buf][0] + rb * 128);
    }
  };

  stage(0, 0);
  int cur = 0;

  for (int t = 0; t < ntB; ++t) {
    if (t + 1 < ntB) { stage(cur ^ 1, t + 1); VMW(4); } else { VMW(0); }
    BARM();
    {
      const int kv0 = t * 64;
      const bool allok = mflag[(b << 5) + t] != 0;

      bf16x8 kb[4][2];
#pragma unroll
      for (int nt = 0; nt < 4; ++nt) {
        const int row = nt * 16 + l15;
#pragma unroll
        for (int ks = 0; ks < 2; ++ks)
          kb[nt][ks] = *(const bf16x8*)((const char*)&ldsK[cur][0] + row * 128 +
                                        ((ks * 64 + g * 16) ^ ((row & 7) << 4)));
      }
      f32x4 s[4];
#pragma unroll
      for (int nt = 0; nt < 4; ++nt) s[nt] = (f32x4){0.f, 0.f, 0.f, 0.f};
      __builtin_amdgcn_s_setprio(1);
#pragma unroll
      for (int nt = 0; nt < 4; ++nt) {
        s[nt] = MFMA16(qa0, kb[nt][0], s[nt]);
        s[nt] = MFMA16(qa1, kb[nt][1], s[nt]);
      }
      __builtin_amdgcn_s_setprio(0);

      if (!allok) {
#pragma unroll
        for (int nt = 0; nt < 4; ++nt) {
          const int pmv = amask[b * S_LEN + kv0 + nt * 16 + l15];
#pragma unroll
          for (int r = 0; r < 4; ++r)
            if (!pmv) s[nt][r] = -1e9f;
        }
      }
      if (t == dTile) {
#pragma unroll
        for (int nt = 0; nt < 4; ++nt) {
          const int kvc = kv0 + nt * 16 + l15;
#pragma unroll
          for (int r = 0; r < 4; ++r)
            s[nt][r] = (kvc <= q0 + g * 4 + r) ? s[nt][r] : -1e9f;
        }
      }

      // fast growth check: per-lane partial max only (no cross-lane reduce)
      float t4[4];
      bool grow = false;
#pragma unroll
      for (int r = 0; r < 4; ++r) {
        t4[r] = fmaxf(fmaxf(s[0][r], s[1][r]), fmaxf(s[2][r], s[3][r]));
        grow = grow || (t4[r] > m[r] + 11.5415603f);   // 8 * log2(e)
      }
      if (__any((int)grow)) {                // rare: exact reduce + rescale
#pragma unroll
        for (int r = 0; r < 4; ++r) {
          float t0 = t4[r];
          t0 = fmaxf(t0, __shfl_xor(t0, 1));
          t0 = fmaxf(t0, __shfl_xor(t0, 2));
          t0 = fmaxf(t0, __shfl_xor(t0, 4));
          t0 = fmaxf(t0, __shfl_xor(t0, 8));
          const float mnew = fmaxf(m[r], t0);
          const float alpha = exp2f(m[r] - mnew);
          m[r] = mnew;
          lacc[r] *= alpha;
#pragma unroll
          for (int dt = 0; dt < 4; ++dt) o[dt][r] *= alpha;
        }
      }
      __bf16* pw = &plds[w][0];
#pragma unroll
      for (int r = 0; r < 4; ++r) {
        const int row = g * 4 + r;
#pragma unroll
        for (int nt = 0; nt < 4; ++nt)
          pw[row * 64 + ((nt * 16 + l15) ^ ((row & 7) << 3))] =
              (__bf16)exp2f(s[nt][r] - m[r]);
      }
      bf16x8 pa0 = *(const bf16x8*)(pw + l15 * 64 + ((g * 8) ^ ((l15 & 7) << 3)));
      bf16x8 pa1 = *(const bf16x8*)(pw + l15 * 64 + ((32 + g * 8) ^ ((l15 & 7) << 3)));
      bf16x8 vb[4][2];
#pragma unroll
      for (int dt = 0; dt < 4; ++dt) {
        const int row = dt * 16 + l15;
#pragma unroll
        for (int ks = 0; ks < 2; ++ks)
          vb[dt][ks] = *(const bf16x8*)((const char*)&ldsV[cur][0] + row * 128 +
                                        ((ks * 64 + g * 16) ^ ((row & 7) << 4)));
      }
      __builtin_amdgcn_s_setprio(1);
      lacc = MFMA16(pa0, ones, lacc);
      lacc = MFMA16(pa1, ones, lacc);
#pragma unroll
      for (int dt = 0; dt < 4; ++dt) {
        o[dt] = MFMA16(pa0, vb[dt][0], o[dt]);
        o[dt] = MFMA16(pa1, vb[dt][1], o[dt]);
      }
      __builtin_amdgcn_s_setprio(0);
    }
    BARM();
    cur ^= 1;
  }

#pragma unroll
  for (int dt = 0; dt < 4; ++dt)
#pragma unroll
    for (int r = 0; r < 4; ++r) {
      const int q = q0 + g * 4 + r;
      ctx[((size_t)(b * S_LEN + q)) * DM + h * DK + dt * 16 + l15] =
          f2bf(o[dt][r] / lacc[r]);
    }
}

extern "C" void kernel_launch(void* const* d_in, const int* in_sizes, int n_in,
                              void* d_out, int out_size, void* d_ws, size_t ws_size,
                              hipStream_t stream) {
  const float* x   = (const float*)d_in[0];
  const int* amask = (const int*)d_in[1];
  const float* wq  = (const float*)d_in[2];
  const float* wk  = (const float*)d_in[3];
  const float* wv  = (const float*)d_in[4];
  const float* wo  = (const float*)d_in[5];
  float* out = (float*)d_out;

  char* ws = (char*)d_ws;
  u16* xb    = (u16*)(ws);                      // 8 MB
  u16* wqb   = (u16*)(ws + ( 8u << 20));        // 2 MB
  u16* wkb   = (u16*)(ws + (10u << 20));
  u16* wvb   = (u16*)(ws + (12u << 20));
  u16* wob   = (u16*)(ws + (14u << 20));
  float2* tab = (float2*)(ws + (16u << 20));    // 512 KB
  int* mflag = (int*)(ws + (16u << 20) + (768u << 10));   // 256 B
  u16* Qr    = (u16*)(ws + (17u << 20));        // 8 MB  [B,H,S,D]
  u16* Kr    = (u16*)(ws + (25u << 20));        // 8 MB  [B,H,S,D]
  u16* Vt    = (u16*)(ws + (33u << 20));        // 8 MB  [B,H,D,S]
  u16* ctx   = (u16*)(ws + (41u << 20));        // 8 MB  [B,S,H*D]

  hipLaunchKernelGGL(prep_all, dim3(2368), dim3(256), 0, stream,
                     x, wq, wk, wv, wo, amask, xb, wqb, wkb, wvb, wob, tab, mflag);
  hipLaunchKernelGGL(gemm_qkv32, dim3(768), dim3(256), 0, stream,
                     xb, wqb, wkb, wvb, tab, Qr, Kr, Vt);
  hipLaunchKernelGGL(attn15, dim3(32, 32), dim3(256), 0, stream,
                     Qr, Kr, Vt, amask, mflag, ctx);
  hipLaunchKernelGGL(gemm_out44, dim3(1024), dim3(256), 0, stream, ctx, wob, out);
}